// Round 1
// baseline (159.003 us; speedup 1.0000x reference)
//
#include <hip/hip_runtime.h>
#include <hip/hip_bf16.h>

// FactorizedTrilinear: out[b,z,x,c,d,v] = sum_e p1[b,z,d,v,e] p2[b,x,d,v,e] p3[b,c,d,v,e]
// p_k = x_k @ W_k + b_k
// B=4, Z=128, D*V=4 ("dv"), IN=512, R=256. Output 4*128^3*4 fp32 = 134 MB.

typedef __attribute__((ext_vector_type(8))) short short8;
typedef __attribute__((ext_vector_type(4))) float f32x4;

__device__ __forceinline__ short f2bf(float f) {
    union { float f; unsigned u; } v; v.f = f;
    unsigned r = v.u + 0x7FFFu + ((v.u >> 16) & 1u);   // RNE to bf16
    return (short)(r >> 16);
}

// ---------------- Stage 1: projections ----------------
// P_k[sl][z][e] with sl = b*4 + d*2 + v, layout [16][128][256].
// Row m in [0,2048): m = ((b*128+z)*2+d)*2+v  (x rows are exactly this order).
// Block: 16 rows x 256 cols. 256 threads: q=tid>>7 (row half), ec=tid&127; thread
// owns rows [q*8,q*8+8) x cols {ec, ec+128} -> 16 acc regs, 2 FMA per LDS float.
__global__ __launch_bounds__(256) void proj_kernel(
    const float* __restrict__ x1, const float* __restrict__ x2, const float* __restrict__ x3,
    const float* __restrict__ W1, const float* __restrict__ b1,
    const float* __restrict__ W2, const float* __restrict__ b2,
    const float* __restrict__ W3, const float* __restrict__ b3,
    short* __restrict__ p1, float* __restrict__ p2, float* __restrict__ p3) {
    const int k = blockIdx.y;
    const float* __restrict__ x    = (k == 0) ? x1 : (k == 1) ? x2 : x3;
    const float* __restrict__ W    = (k == 0) ? W1 : (k == 1) ? W2 : W3;
    const float* __restrict__ bias = (k == 0) ? b1 : (k == 1) ? b2 : b3;

    const int tid = threadIdx.x;
    const int m0  = blockIdx.x * 16;
    const int q   = tid >> 7;       // row half
    const int ec  = tid & 127;      // first owned column

    __shared__ __align__(16) float sx[16 * 64];   // 16 rows x 64-i chunk

    float acc[8][2];
#pragma unroll
    for (int r = 0; r < 8; ++r) { acc[r][0] = 0.f; acc[r][1] = 0.f; }

    for (int c8 = 0; c8 < 8; ++c8) {
        const int i0 = c8 * 64;
        // stage x chunk: 256 granules of float4, one per thread
        {
            const int r = tid >> 4, j = tid & 15;
            f32x4 v = *(const f32x4*)(x + (size_t)(m0 + r) * 512 + i0 + j * 4);
            *(f32x4*)&sx[r * 64 + j * 4] = v;
        }
        __syncthreads();
#pragma unroll 4
        for (int iq = 0; iq < 16; ++iq) {
            float w0[4], w1[4];
#pragma unroll
            for (int t = 0; t < 4; ++t) {
                w0[t] = W[(i0 + iq * 4 + t) * 256 + ec];
                w1[t] = W[(i0 + iq * 4 + t) * 256 + ec + 128];
            }
#pragma unroll
            for (int r = 0; r < 8; ++r) {
                f32x4 xv = *(const f32x4*)&sx[(q * 8 + r) * 64 + iq * 4];
#pragma unroll
                for (int t = 0; t < 4; ++t) {
                    acc[r][0] = fmaf(xv[t], w0[t], acc[r][0]);
                    acc[r][1] = fmaf(xv[t], w1[t], acc[r][1]);
                }
            }
        }
        __syncthreads();
    }

#pragma unroll
    for (int r = 0; r < 8; ++r) {
        const int m = m0 + q * 8 + r;
        const int bb = m >> 9, z = (m >> 2) & 127, dvv = m & 3;
#pragma unroll
        for (int j = 0; j < 2; ++j) {
            const int e = ec + j * 128;
            const float val = acc[r][j] + bias[e];
            const int off = ((bb * 4 + dvv) * 128 + z) * 256 + e;
            if (k == 0)      p1[off] = f2bf(val);
            else if (k == 1) p2[off] = val;
            else             p3[off] = val;
        }
    }
}

// ---------------- Stage 2: trilinear via bf16 MFMA ----------------
// Block: (b, x, ct) with ct = c-half (64 cols). Computes Out[z=128][c=64][dv=4],
// stores float4 over dv (innermost output dims) -> fully coalesced 16B stores.
// LDS granule layout (16B granules = 8 bf16 along k):
//   sA[(dv*4+kg)*128 + z] = p1[sl][z][e0 + kg*8 .. +8]   (32 KB per 32-wide e-chunk)
//   sQ[(dv*4+kg)*64  + c] = p2[sl][x][..] * p3[sl][c][..] in bf16 (16 KB)
// Fragment reads: lane l -> granule row (l&15), k-group (l>>4): consecutive lanes
// hit consecutive 16B granules -> conflict-free ds_read_b128.
// 4 waves: wz = w>>1 (z half, 64 rows), wc = w&1 (c half, 32 cols).
// Per wave acc: 4 z-tiles x 2 c-tiles x 4 dv = 32 frags (128 VGPRs).
__global__ __launch_bounds__(256, 2) void tri_kernel(
    const short* __restrict__ p1, const float* __restrict__ p2,
    const float* __restrict__ p3, float* __restrict__ out) {
    const int i  = blockIdx.x;
    const int ct = i & 1;
    const int x  = (i >> 1) & 127;
    const int b  = i >> 8;

    const int tid  = threadIdx.x;
    const int lane = tid & 63;
    const int w    = tid >> 6;
    const int wz   = w >> 1, wc = w & 1;
    const int kq   = lane >> 4, ln = lane & 15;

    __shared__ __align__(16) short sA[2048 * 8];   // 32 KB
    __shared__ __align__(16) short sQ[1024 * 8];   // 16 KB

    f32x4 acc[4][2][4];
    const f32x4 zero = {0.f, 0.f, 0.f, 0.f};
#pragma unroll
    for (int zt = 0; zt < 4; ++zt)
#pragma unroll
        for (int c2 = 0; c2 < 2; ++c2)
#pragma unroll
            for (int dv = 0; dv < 4; ++dv) acc[zt][c2][dv] = zero;

#pragma unroll 1
    for (int chunk = 0; chunk < 8; ++chunk) {
        const int e0 = chunk * 32;

        // --- stage A: 2048 granules, 8 per thread ---
#pragma unroll
        for (int it = 0; it < 8; ++it) {
            const int G  = it * 256 + tid;
            const int dv = G >> 9, kg = (G >> 7) & 3, zz = G & 127;
            const int src = ((b * 4 + dv) * 128 + zz) * 256 + e0 + kg * 8;
            short8 v = *(const short8*)(p1 + src);
            *(short8*)&sA[G * 8] = v;
        }
        // --- stage Q: 1024 granules, 4 per thread ---
#pragma unroll
        for (int it = 0; it < 4; ++it) {
            const int G  = it * 256 + tid;
            const int dv = G >> 8, kg = (G >> 6) & 3, cc = G & 63;
            const int sl = b * 4 + dv;
            const int eb = e0 + kg * 8;
            const float* P2 = p2 + ((size_t)(sl * 128 + x) * 256 + eb);
            const float* P3 = p3 + ((size_t)(sl * 128 + (ct * 64 + cc)) * 256 + eb);
            f32x4 a0 = *(const f32x4*)P2;
            f32x4 a1 = *(const f32x4*)(P2 + 4);
            f32x4 q0 = *(const f32x4*)P3;
            f32x4 q1 = *(const f32x4*)(P3 + 4);
            short8 qv;
            qv[0] = f2bf(a0[0] * q0[0]); qv[1] = f2bf(a0[1] * q0[1]);
            qv[2] = f2bf(a0[2] * q0[2]); qv[3] = f2bf(a0[3] * q0[3]);
            qv[4] = f2bf(a1[0] * q1[0]); qv[5] = f2bf(a1[1] * q1[1]);
            qv[6] = f2bf(a1[2] * q1[2]); qv[7] = f2bf(a1[3] * q1[3]);
            *(short8*)&sQ[G * 8] = qv;
        }
        __syncthreads();

        // --- MFMA phase: one k-step (k=32) per chunk ---
#pragma unroll
        for (int dv = 0; dv < 4; ++dv) {
            short8 af[4], bfr[2];
#pragma unroll
            for (int zt = 0; zt < 4; ++zt)
                af[zt] = *(const short8*)&sA[((dv * 4 + kq) * 128 + wz * 64 + zt * 16 + ln) * 8];
#pragma unroll
            for (int c2 = 0; c2 < 2; ++c2)
                bfr[c2] = *(const short8*)&sQ[((dv * 4 + kq) * 64 + wc * 32 + c2 * 16 + ln) * 8];
#pragma unroll
            for (int zt = 0; zt < 4; ++zt)
#pragma unroll
                for (int c2 = 0; c2 < 2; ++c2)
                    acc[zt][c2][dv] = __builtin_amdgcn_mfma_f32_16x16x32_bf16(
                        af[zt], bfr[c2], acc[zt][c2][dv], 0, 0, 0);
        }
        __syncthreads();
    }

    // --- epilogue: float4 over dv, coalesced ---
#pragma unroll
    for (int zt = 0; zt < 4; ++zt)
#pragma unroll
        for (int c2 = 0; c2 < 2; ++c2)
#pragma unroll
            for (int r = 0; r < 4; ++r) {
                const int z = wz * 64 + zt * 16 + kq * 4 + r;
                const int c = ct * 64 + wc * 32 + c2 * 16 + ln;
                const size_t idx = (size_t)((b * 128 + z) * 128 + x) * 128 + c;
                f32x4 v;
                v[0] = acc[zt][c2][0][r];
                v[1] = acc[zt][c2][1][r];
                v[2] = acc[zt][c2][2][r];
                v[3] = acc[zt][c2][3][r];
                *(f32x4*)(out + idx * 4) = v;
            }
}

extern "C" void kernel_launch(void* const* d_in, const int* in_sizes, int n_in,
                              void* d_out, int out_size, void* d_ws, size_t ws_size,
                              hipStream_t stream) {
    const float* x1 = (const float*)d_in[0];
    const float* x2 = (const float*)d_in[1];
    const float* x3 = (const float*)d_in[2];
    const float* W1 = (const float*)d_in[3];
    const float* b1 = (const float*)d_in[4];
    const float* W2 = (const float*)d_in[5];
    const float* b2 = (const float*)d_in[6];
    const float* W3 = (const float*)d_in[7];
    const float* b3 = (const float*)d_in[8];

    char* ws = (char*)d_ws;
    short* p1 = (short*)ws;                       // bf16 [16][128][256] = 1 MB
    float* p2 = (float*)(ws + (1u << 20));        // f32  [16][128][256] = 2 MB
    float* p3 = (float*)(ws + 3u * (1u << 20));   // f32  [16][128][256] = 2 MB

    proj_kernel<<<dim3(128, 3), 256, 0, stream>>>(x1, x2, x3, W1, b1, W2, b2, W3, b3,
                                                  p1, p2, p3);
    tri_kernel<<<dim3(1024), 256, 0, stream>>>(p1, p2, p3, (float*)d_out);
}